// Round 13
// baseline (210.802 us; speedup 1.0000x reference)
//
#include <hip/hip_runtime.h>
#include <math.h>

typedef __attribute__((ext_vector_type(8))) short bf16x8;
typedef __attribute__((ext_vector_type(4))) float f32x4;
typedef unsigned short u16;
typedef unsigned int u32;

static __device__ __forceinline__ u16 f2bf(float f) {
    unsigned u = __float_as_uint(f);
    unsigned r = (u + 0x7fff + ((u >> 16) & 1)) >> 16;  // RNE
    return (u16)r;
}
static __device__ __forceinline__ float bf2f(u16 h) {
    return __uint_as_float(((unsigned)h) << 16);
}
static __device__ __forceinline__ float pk_lo(u32 u) { return __uint_as_float(u << 16); }
static __device__ __forceinline__ float pk_hi(u32 u) { return __uint_as_float(u & 0xffff0000u); }

// ---------------- weight prepack only ----------------
__global__ void initw_k(const float* __restrict__ W0, const float* __restrict__ W1,
                        const float* __restrict__ W2,
                        u16* __restrict__ w0hi, u16* __restrict__ w0lo,
                        u16* __restrict__ w1hi, u16* __restrict__ w1lo,
                        u16* __restrict__ w2hi, u16* __restrict__ w2lo) {
    int i = blockIdx.x * 256 + threadIdx.x;
    const float* W; u16 *hi, *lo; int COLS, cin, idx;
    if (i < 16384)      { W = W0; hi = w0hi; lo = w0lo; COLS = 128; cin = 128; idx = i; }
    else if (i < 32768) { W = W1; hi = w1hi; lo = w1lo; COLS = 128; cin = 128; idx = i - 16384; }
    else if (i < 40960) { W = W2; hi = w2hi; lo = w2lo; COLS = 64;  cin = 40;  idx = i - 32768; }
    else return;
    int k = idx / COLS, col = idx % COLS;
    float v = (col < cin) ? W[k * cin + col] : 0.f;
    u16 h = f2bf(v);
    u16 l = f2bf(v - bf2f(h));
    int ct = col >> 4, ks = k >> 5, ln = (col & 15) + (((k >> 3) & 3) << 4), j = k & 7;
    int pos = (((ct * 4 + ks) * 64 + ln) << 3) + j;
    hi[pos] = h; lo[pos] = l;
}

// ---------------- LDS-privatized histogram + local rank ----------------
// 256 blocks; block b handles edges [b*epb, b*epb+epb). Bins packed 2-per-u32;
// two halves of <=12544 words each to stay within static LDS. slab[b][w] = packed counts.
__global__ __launch_bounds__(512) void hist_k(const int* __restrict__ dst,
                                              u32* __restrict__ slab,
                                              u16* __restrict__ rank,
                                              int e, int epb, int nw) {
    __shared__ u32 h[12544];
    int b = blockIdx.x, tid = threadIdx.x;
    int start = b * epb, end = min(e, start + epb);
    int half_w = (nw + 1) / 2;
    for (int half = 0; half < 2; ++half) {
        int w0 = half * half_w;
        int wn = min(half_w, nw - w0);
        if (wn <= 0) break;
        for (int w = tid; w < wn; w += 512) h[w] = 0;
        __syncthreads();
        for (int i = start + tid; i < end; i += 512) {
            int d = dst[i];
            int wd = d >> 1;
            if (wd >= w0 && wd < w0 + wn) {
                u32 sh = (u32)(d & 1) << 4;
                u32 old = atomicAdd(&h[wd - w0], 1u << sh);
                rank[i] = (u16)((old >> sh) & 0xffffu);
            }
        }
        __syncthreads();
        u32* row = slab + (size_t)b * nw + w0;
        for (int w = tid; w < wn; w += 512) row[w] = h[w];
        if (half == 0) __syncthreads();
    }
}

// ---------------- slab scan along block axis (16 groups x 16 blocks) ----------------
__global__ void pscanA_k(const u32* __restrict__ slab, u32* __restrict__ gsum, int nw) {
    int id = blockIdx.x * 256 + threadIdx.x;
    if (id >= 16 * nw) return;
    int g = id / nw, w = id - g * nw;
    const u32* base = slab + (size_t)(g * 16) * nw + w;
    u32 s = 0;
#pragma unroll
    for (int j = 0; j < 16; ++j) s += base[(size_t)j * nw];
    gsum[(size_t)g * nw + w] = s;
}
__global__ void pscanB_k(u32* __restrict__ gsum, int* __restrict__ counts, int nw) {
    int w = blockIdx.x * 256 + threadIdx.x;
    if (w >= nw) return;
    u32 run = 0;
#pragma unroll
    for (int g = 0; g < 16; ++g) {
        u32 v = gsum[(size_t)g * nw + w];
        gsum[(size_t)g * nw + w] = run;
        run += v;
    }
    counts[2 * w] = (int)(run & 0xffffu);
    counts[2 * w + 1] = (int)(run >> 16);
}
__global__ void pscanC_k(u32* __restrict__ slab, const u32* __restrict__ gsum, int nw) {
    int id = blockIdx.x * 256 + threadIdx.x;
    if (id >= 16 * nw) return;
    int g = id / nw, w = id - g * nw;
    u32 run = gsum[(size_t)g * nw + w];
    u32* base = slab + (size_t)(g * 16) * nw + w;
#pragma unroll
    for (int j = 0; j < 16; ++j) {
        u32 v = base[(size_t)j * nw];
        base[(size_t)j * nw] = run;
        run += v;
    }
}

// ---------------- offs scans (unchanged) ----------------
__global__ __launch_bounds__(1024) void scan1_k(const int* __restrict__ counts,
                                                int* __restrict__ offs,
                                                int* __restrict__ bsum,
                                                float* __restrict__ dinv, int n) {
    __shared__ int ws[16];
    int tid = threadIdx.x;
    int i = blockIdx.x * 1024 + tid;
    int lane = tid & 63, w = tid >> 6;
    int c = (i < n) ? counts[i] : 0;
    if (i < n) dinv[i] = rsqrtf((float)c + 1.0f);
    int s = c;
#pragma unroll
    for (int o = 1; o < 64; o <<= 1) { int t = __shfl_up(s, o); if (lane >= o) s += t; }
    if (lane == 63) ws[w] = s;
    __syncthreads();
    if (w == 0) {
        int x = (lane < 16) ? ws[lane] : 0;
#pragma unroll
        for (int o = 1; o < 16; o <<= 1) { int t = __shfl_up(x, o); if (lane >= o) x += t; }
        if (lane < 16) ws[lane] = x;
    }
    __syncthreads();
    int base = (w > 0) ? ws[w - 1] : 0;
    int incl = base + s;
    if (i < n) offs[i + 1] = incl;
    if (tid == 1023) bsum[blockIdx.x] = incl;
}
__global__ void scan23_k(int* __restrict__ offs, const int* __restrict__ bsum,
                         int nb, int n) {
    __shared__ int pre[64];
    int tid = threadIdx.x;
    if (tid < 64) {
        int v = (tid < nb) ? bsum[tid] : 0;
#pragma unroll
        for (int o = 1; o < 64; o <<= 1) { int t = __shfl_up(v, o); if (tid >= o) v += t; }
        pre[tid] = v;
    }
    __syncthreads();
    int i = blockIdx.x * 256 + tid;
    if (i == 0) offs[0] = 0;
    if (i < n) {
        int b = i >> 10;
        offs[i + 1] += (b > 0) ? pre[b - 1] : 0;
    }
}

// ---------------- layer-1 GEMM body: fp32 A, hi/lo 3-MFMA, UNSCALED bf16 C ----------------
static __device__ __forceinline__ void gemm1_body(int bid, const float* __restrict__ A,
                                                  const u16* __restrict__ Whi,
                                                  const u16* __restrict__ Wlo,
                                                  u16* __restrict__ C, int nrows) {
    constexpr int COLS = 128;
    int wave = threadIdx.x >> 6, lane = threadIdx.x & 63;
    int r0 = bid * 64 + wave * 16;
    int arow = min(r0 + (lane & 15), nrows - 1);
    int kbase = (lane >> 4) * 8;

    bf16x8 ahi[4], alo[4];
#pragma unroll
    for (int ks = 0; ks < 4; ++ks) {
        const float* ap = &A[(long)arow * 128 + ks * 32 + kbase];
        float4 f0 = *(const float4*)ap;
        float4 f1 = *(const float4*)(ap + 4);
        float fv[8] = {f0.x, f0.y, f0.z, f0.w, f1.x, f1.y, f1.z, f1.w};
#pragma unroll
        for (int j = 0; j < 8; ++j) {
            u16 h = f2bf(fv[j]);
            ahi[ks][j] = (short)h;
            alo[ks][j] = (short)f2bf(fv[j] - bf2f(h));
        }
    }
#pragma unroll
    for (int ct = 0; ct < COLS / 16; ct += 2) {
        f32x4 acc0 = {0.f, 0.f, 0.f, 0.f}, acc1 = {0.f, 0.f, 0.f, 0.f};
#pragma unroll
        for (int ks = 0; ks < 4; ++ks) {
            int fo0 = ((ct * 4 + ks) * 64 + lane) * 8;
            int fo1 = (((ct + 1) * 4 + ks) * 64 + lane) * 8;
            bf16x8 bhi0 = *(const bf16x8*)&Whi[fo0];
            bf16x8 blo0 = *(const bf16x8*)&Wlo[fo0];
            bf16x8 bhi1 = *(const bf16x8*)&Whi[fo1];
            bf16x8 blo1 = *(const bf16x8*)&Wlo[fo1];
            acc0 = __builtin_amdgcn_mfma_f32_16x16x32_bf16(ahi[ks], bhi0, acc0, 0, 0, 0);
            acc1 = __builtin_amdgcn_mfma_f32_16x16x32_bf16(ahi[ks], bhi1, acc1, 0, 0, 0);
            acc0 = __builtin_amdgcn_mfma_f32_16x16x32_bf16(alo[ks], bhi0, acc0, 0, 0, 0);
            acc1 = __builtin_amdgcn_mfma_f32_16x16x32_bf16(alo[ks], bhi1, acc1, 0, 0, 0);
            acc0 = __builtin_amdgcn_mfma_f32_16x16x32_bf16(ahi[ks], blo0, acc0, 0, 0, 0);
            acc1 = __builtin_amdgcn_mfma_f32_16x16x32_bf16(ahi[ks], blo1, acc1, 0, 0, 0);
        }
#pragma unroll
        for (int r = 0; r < 4; ++r) {
            int orow = r0 + (lane >> 4) * 4 + r;
            if (orow < nrows) {
                C[(long)orow * COLS + ct * 16 + (lane & 15)] = f2bf(acc0[r]);
                C[(long)orow * COLS + (ct + 1) * 16 + (lane & 15)] = f2bf(acc1[r]);
            }
        }
    }
}

// ---------------- fill (atomic-free, slab bases) || layer-1 GEMM, 4:1 ----------------
__global__ __launch_bounds__(256) void fg1_k(const int* __restrict__ esrc,
                                             const int* __restrict__ edst,
                                             const u16* __restrict__ rank,
                                             const int* __restrict__ offs,
                                             const u32* __restrict__ slab,
                                             u16* __restrict__ csr,
                                             int e, int epb, int nw,
                                             const float* __restrict__ A,
                                             const u16* __restrict__ Whi,
                                             const u16* __restrict__ Wlo,
                                             u16* __restrict__ C, int nrows, int gemmBlocks) {
    int bid = blockIdx.x;
    int k = bid / 5, r = bid % 5;
    if (r == 4) {
        if (k < gemmBlocks) gemm1_body(k, A, Whi, Wlo, C, nrows);
        return;
    }
    int i = (k * 4 + r) * 256 + threadIdx.x;
    if (i < e) {
        int d = edst[i];
        int b = i / epb;
        u32 word = slab[(size_t)b * nw + (d >> 1)];
        int base = (int)((word >> ((u32)(d & 1) << 4)) & 0xffffu);
        csr[offs[d] + base + (int)rank[i]] = (u16)esrc[i];
    }
}

// ---------------- bf16-A GEMM body (2 MFMA), dinv-prescaled C, row range ----------------
template<int COLS>
static __device__ __forceinline__ void gemm_body(int bid, const u16* __restrict__ A,
                                                 const u16* __restrict__ Whi,
                                                 const u16* __restrict__ Wlo,
                                                 const float* __restrict__ dinv,
                                                 u16* __restrict__ C, int rowOff, int rowEnd) {
    int wave = threadIdx.x >> 6, lane = threadIdx.x & 63;
    int r0 = rowOff + bid * 64 + wave * 16;
    if (r0 >= rowEnd) return;
    int arow = min(r0 + (lane & 15), rowEnd - 1);
    int kbase = (lane >> 4) * 8;

    bf16x8 a[4];
#pragma unroll
    for (int ks = 0; ks < 4; ++ks)
        a[ks] = *(const bf16x8*)&A[(long)arow * 128 + ks * 32 + kbase];

    float dscale[4];
#pragma unroll
    for (int r = 0; r < 4; ++r) {
        int orow = r0 + (lane >> 4) * 4 + r;
        dscale[r] = (orow < rowEnd) ? dinv[orow] : 0.f;
    }
#pragma unroll
    for (int ct = 0; ct < COLS / 16; ct += 2) {
        f32x4 acc0 = {0.f, 0.f, 0.f, 0.f}, acc1 = {0.f, 0.f, 0.f, 0.f};
#pragma unroll
        for (int ks = 0; ks < 4; ++ks) {
            int fo0 = ((ct * 4 + ks) * 64 + lane) * 8;
            int fo1 = (((ct + 1) * 4 + ks) * 64 + lane) * 8;
            bf16x8 bhi0 = *(const bf16x8*)&Whi[fo0];
            bf16x8 blo0 = *(const bf16x8*)&Wlo[fo0];
            bf16x8 bhi1 = *(const bf16x8*)&Whi[fo1];
            bf16x8 blo1 = *(const bf16x8*)&Wlo[fo1];
            acc0 = __builtin_amdgcn_mfma_f32_16x16x32_bf16(a[ks], bhi0, acc0, 0, 0, 0);
            acc1 = __builtin_amdgcn_mfma_f32_16x16x32_bf16(a[ks], bhi1, acc1, 0, 0, 0);
            acc0 = __builtin_amdgcn_mfma_f32_16x16x32_bf16(a[ks], blo0, acc0, 0, 0, 0);
            acc1 = __builtin_amdgcn_mfma_f32_16x16x32_bf16(a[ks], blo1, acc1, 0, 0, 0);
        }
#pragma unroll
        for (int r = 0; r < 4; ++r) {
            int orow = r0 + (lane >> 4) * 4 + r;
            if (orow < rowEnd) {
                C[(long)orow * COLS + ct * 16 + (lane & 15)] = f2bf(acc0[r] * dscale[r]);
                C[(long)orow * COLS + (ct + 1) * 16 + (lane & 15)] = f2bf(acc1[r] * dscale[r]);
            }
        }
    }
}

// ---------------- agg + bias + LN + ReLU body; PRESCALED=false folds dinv[src] ----------------
template<bool PRESCALED>
static __device__ __forceinline__ void agg_ln_body(int wid, int lane,
                                                   const u16* __restrict__ Cs,
                                                   const int* __restrict__ offs,
                                                   const u16* __restrict__ csr,
                                                   const float* __restrict__ dinv,
                                                   const float* __restrict__ bias,
                                                   const float* __restrict__ g,
                                                   const float* __restrict__ b,
                                                   u16* __restrict__ out) {
    const u32* C2 = (const u32*)Cs;
    u32 su = C2[(long)wid * 64 + lane];
    float ss = PRESCALED ? 1.f : dinv[wid];
    float ax = pk_lo(su) * ss, ay = pk_hi(su) * ss, bx2 = 0.f, by2 = 0.f;
    int beg = offs[wid], end = offs[wid + 1];
    int j = beg;
    while (j < end) {
        int take = min(64, end - j);
        int myidx = (lane < take) ? (int)csr[j + lane] : 0;
        int k = 0;
        for (; k + 8 <= take; k += 8) {
            int is[8];
#pragma unroll
            for (int q = 0; q < 8; ++q) is[q] = __shfl(myidx, k + q);
            float ds[8];
            if (!PRESCALED) {
#pragma unroll
                for (int q = 0; q < 8; ++q) ds[q] = dinv[is[q]];
            }
            u32 us[8];
#pragma unroll
            for (int q = 0; q < 8; ++q) us[q] = C2[(long)is[q] * 64 + lane];
#pragma unroll
            for (int q = 0; q < 8; ++q) {
                float f0 = pk_lo(us[q]), f1 = pk_hi(us[q]);
                if (!PRESCALED) { f0 *= ds[q]; f1 *= ds[q]; }
                if (q < 4) { ax += f0; ay += f1; }
                else       { bx2 += f0; by2 += f1; }
            }
        }
        for (; k < take; ++k) {
            int i0 = __shfl(myidx, k);
            float dv = PRESCALED ? 1.f : dinv[i0];
            u32 u0 = C2[(long)i0 * 64 + lane];
            ax += pk_lo(u0) * dv; ay += pk_hi(u0) * dv;
        }
        j += take;
    }
    float w = dinv[wid];
    float2 bia = ((const float2*)bias)[lane];
    float t0 = (ax + bx2) * w + bia.x;
    float t1 = (ay + by2) * w + bia.y;
    float s = t0 + t1;
#pragma unroll
    for (int off = 32; off; off >>= 1) s += __shfl_xor(s, off);
    float mu = s * (1.f / 128.f);
    float d0 = t0 - mu, d1 = t1 - mu;
    float v = d0 * d0 + d1 * d1;
#pragma unroll
    for (int off = 32; off; off >>= 1) v += __shfl_xor(v, off);
    float rstd = rsqrtf(v * (1.f / 128.f) + 1e-5f);
    float2 gv = ((const float2*)g)[lane];
    float2 bv = ((const float2*)b)[lane];
    float y0 = fmaxf(0.f, d0 * rstd * gv.x + bv.x);
    float y1 = fmaxf(0.f, d1 * rstd * gv.y + bv.y);
    ((u32*)out)[(long)wid * 64 + lane] = ((u32)f2bf(y1) << 16) | f2bf(y0);
}

template<bool PRESCALED>
__global__ __launch_bounds__(256) void agg_half_k(const u16* __restrict__ Cs,
                                                  const int* __restrict__ offs,
                                                  const u16* __restrict__ csr,
                                                  const float* __restrict__ dinv,
                                                  const float* __restrict__ bias,
                                                  const float* __restrict__ g,
                                                  const float* __restrict__ b,
                                                  u16* __restrict__ out,
                                                  int nodeOff, int nodeEnd) {
    int wid = nodeOff + ((blockIdx.x * 256 + threadIdx.x) >> 6);
    int lane = threadIdx.x & 63;
    if (wid >= nodeEnd) return;
    agg_ln_body<PRESCALED>(wid, lane, Cs, offs, csr, dinv, bias, g, b, out);
}

template<int COLS, bool PRESCALED>
__global__ __launch_bounds__(256) void aggemm_k(const u16* __restrict__ CsAgg,
                                                const int* __restrict__ offs,
                                                const u16* __restrict__ csr,
                                                const float* __restrict__ dinv,
                                                const float* __restrict__ bias,
                                                const float* __restrict__ g,
                                                const float* __restrict__ b,
                                                u16* __restrict__ hOut,
                                                int nodeOff, int nodeEnd,
                                                const u16* __restrict__ A,
                                                const u16* __restrict__ Whi,
                                                const u16* __restrict__ Wlo,
                                                u16* __restrict__ C, int rowEnd, int gemmBlocks) {
    int bid = blockIdx.x;
    int k = bid / 17, r = bid % 17;
    if (r == 16) {
        if (k < gemmBlocks) gemm_body<COLS>(k, A, Whi, Wlo, dinv, C, 0, rowEnd);
        return;
    }
    int aggIdx = k * 16 + r;
    int wid = nodeOff + ((aggIdx * 256 + (int)threadIdx.x) >> 6);
    int lane = threadIdx.x & 63;
    if (wid >= nodeEnd) return;
    agg_ln_body<PRESCALED>(wid, lane, CsAgg, offs, csr, dinv, bias, g, b, hOut);
}

template<int COLS>
__global__ __launch_bounds__(256) void gemm_half_k(const u16* __restrict__ A,
                                                   const u16* __restrict__ Whi,
                                                   const u16* __restrict__ Wlo,
                                                   const float* __restrict__ dinv,
                                                   u16* __restrict__ C, int rowOff, int rowEnd) {
    gemm_body<COLS>(blockIdx.x, A, Whi, Wlo, dinv, C, rowOff, rowEnd);
}

// ---------------- agg + bias + log_softmax (8-deep, 64-col Cs) ----------------
__global__ __launch_bounds__(256) void agg_lsm_k(const u16* __restrict__ Cs,
                                                 const int* __restrict__ offs,
                                                 const u16* __restrict__ csr,
                                                 const float* __restrict__ dinv,
                                                 const float* __restrict__ b2,
                                                 float* __restrict__ out, int n) {
    int wid = (blockIdx.x * 256 + threadIdx.x) >> 6;
    int lane = threadIdx.x & 63;
    if (wid >= n) return;
    float aa = bf2f(Cs[(long)wid * 64 + lane]), ab = 0.f;
    int beg = offs[wid], end = offs[wid + 1];
    int j = beg;
    while (j < end) {
        int take = min(64, end - j);
        int myidx = (lane < take) ? (int)csr[j + lane] : 0;
        int k = 0;
        for (; k + 8 <= take; k += 8) {
            int i0 = __shfl(myidx, k),     i1 = __shfl(myidx, k + 1);
            int i2 = __shfl(myidx, k + 2), i3 = __shfl(myidx, k + 3);
            int i4 = __shfl(myidx, k + 4), i5 = __shfl(myidx, k + 5);
            int i6 = __shfl(myidx, k + 6), i7 = __shfl(myidx, k + 7);
            float v0 = bf2f(Cs[(long)i0 * 64 + lane]), v1 = bf2f(Cs[(long)i1 * 64 + lane]);
            float v2 = bf2f(Cs[(long)i2 * 64 + lane]), v3 = bf2f(Cs[(long)i3 * 64 + lane]);
            float v4 = bf2f(Cs[(long)i4 * 64 + lane]), v5 = bf2f(Cs[(long)i5 * 64 + lane]);
            float v6 = bf2f(Cs[(long)i6 * 64 + lane]), v7 = bf2f(Cs[(long)i7 * 64 + lane]);
            aa += v0 + v1 + v2 + v3;
            ab += v4 + v5 + v6 + v7;
        }
        for (; k < take; ++k) {
            int i0 = __shfl(myidx, k);
            aa += bf2f(Cs[(long)i0 * 64 + lane]);
        }
        j += take;
    }
    float v = (lane < 40) ? (aa + ab) * dinv[wid] + b2[lane] : -INFINITY;
    float m = v;
#pragma unroll
    for (int off = 32; off; off >>= 1) m = fmaxf(m, __shfl_xor(m, off));
    float e = (lane < 40) ? expf(v - m) : 0.f;
    float s = e;
#pragma unroll
    for (int off = 32; off; off >>= 1) s += __shfl_xor(s, off);
    float r = v - m - logf(s);
    if (lane < 40) out[(long)wid * 40 + lane] = r;
}

extern "C" void kernel_launch(void* const* d_in, const int* in_sizes, int n_in,
                              void* d_out, int out_size, void* d_ws, size_t ws_size,
                              hipStream_t stream) {
    const float* x    = (const float*)d_in[0];
    const float* W0   = (const float*)d_in[1];
    const float* b0   = (const float*)d_in[2];
    const float* W1   = (const float*)d_in[3];
    const float* b1   = (const float*)d_in[4];
    const float* W2   = (const float*)d_in[5];
    const float* b2   = (const float*)d_in[6];
    const float* ln1g = (const float*)d_in[7];
    const float* ln1b = (const float*)d_in[8];
    const float* ln2g = (const float*)d_in[9];
    const float* ln2b = (const float*)d_in[10];
    const int*   ei   = (const int*)d_in[11];

    const int N = in_sizes[0] / 128;   // 50000
    const int E = in_sizes[11] / 2;    // 800000
    const int* esrc = ei;
    const int* edst = ei + E;
    float* out = (float*)d_out;

    const int Npad = ((N + 255) / 256) * 256;
    const int N2 = N / 2;
    const int NW = (N + 1) / 2;        // packed histogram words (25000)
    const int EPB = (E + 255) / 256;   // edges per hist block (3125)

    int* counts  = (int*)d_ws;                        // Npad
    int* offs    = counts + Npad;                     // Npad (N+1 used)
    int* bsum    = offs + Npad;                       // 64
    u16* rank16  = (u16*)(bsum + 64);                 // E
    u16* csr16   = rank16 + E;                        // E
    float* dinv  = (float*)(csr16 + E);               // Npad
    u16* bufA    = (u16*)(dinv + Npad);               // N*128 bf16  (Cs1 unscaled, later h2)
    u16* bufB    = bufA + (size_t)N * 128;            // N*128 bf16  (h1, later Cs3) -- slab aliases bufB..bufC
    u16* bufC    = bufB + (size_t)N * 128;            // N*128 bf16  (Cs2)
    u16* w0hi    = bufC + (size_t)N * 128;
    u16* w0lo    = w0hi + 16384;
    u16* w1hi    = w0lo + 16384;
    u16* w1lo    = w1hi + 16384;
    u16* w2hi    = w1lo + 16384;
    u16* w2lo    = w2hi + 8192;
    u32* gsum    = (u32*)(w2lo + 8192);               // 16*NW (1.6MB)
    u32* slab    = (u32*)bufB;                        // 256*NW u32 = 25.6MB (aliases bufB+bufC, dead before step 9)

    dim3 blk(256);
    int gN = (N + 255) / 256;                 // 196
    int nb1024 = (N + 1023) / 1024;           // 49
    int gG = (N + 63) / 64;                   // 782
    int gGh = (N2 + 63) / 64;                 // 391
    int gAh = (N2 + 3) / 4;                   // 6250
    int gW = (N + 3) / 4;                     // 12500
    int gA16 = (16 * NW + 255) / 256;         // 1563
    int gB1 = (NW + 255) / 256;               // 98

    // 1. weight prepack
    initw_k<<<160, blk, 0, stream>>>(W0, W1, W2, w0hi, w0lo, w1hi, w1lo, w2hi, w2lo);
    // 2. LDS-privatized histogram + local ranks -> slab[256][NW]
    hist_k<<<256, 512, 0, stream>>>(edst, slab, rank16, E, EPB, NW);
    // 3-5. slab scan along block axis (exclusive bases) + per-bin totals -> counts
    pscanA_k<<<gA16, blk, 0, stream>>>(slab, gsum, NW);
    pscanB_k<<<gB1, blk, 0, stream>>>(gsum, counts, NW);
    pscanC_k<<<gA16, blk, 0, stream>>>(slab, gsum, NW);
    // 6-7. offs scan + dinv
    scan1_k<<<nb1024, 1024, 0, stream>>>(counts, offs, bsum, dinv, N);
    scan23_k<<<gN, blk, 0, stream>>>(offs, bsum, nb1024, N);
    // 8. atomic-free CSR fill || layer-1 GEMM (unscaled bf16 -> bufA), 4:1
    fg1_k<<<5 * gG, blk, 0, stream>>>(esrc, edst, rank16, offs, slab, csr16, E, EPB, NW,
                                      x, w0hi, w0lo, bufA, N, gG);
    // 9. agg1 first half (dinv[src] folded): bufA -> h1 bufB[0,N2)
    agg_half_k<false><<<gAh, blk, 0, stream>>>(bufA, offs, csr16, dinv, b0, ln1g, ln1b, bufB, 0, N2);
    // 10. agg1 second half || gemm2 first half (h1[0,N2) -> Cs2 bufC[0,N2))
    aggemm_k<128, false><<<17 * gGh, blk, 0, stream>>>(bufA, offs, csr16, dinv, b0, ln1g, ln1b, bufB,
                                                       N2, N, bufB, w1hi, w1lo, bufC, N2, gGh);
    // 11. gemm2 second half
    gemm_half_k<128><<<gGh, blk, 0, stream>>>(bufB, w1hi, w1lo, dinv, bufC, N2, N);
    // 12. agg2 first half: bufC -> h2 bufA[0,N2)
    agg_half_k<true><<<gAh, blk, 0, stream>>>(bufC, offs, csr16, dinv, b1, ln2g, ln2b, bufA, 0, N2);
    // 13. agg2 second half || gemm3 first half (h2[0,N2) -> Cs3 bufB[0,N2) 64-col)
    aggemm_k<64, true><<<17 * gGh, blk, 0, stream>>>(bufC, offs, csr16, dinv, b1, ln2g, ln2b, bufA,
                                                     N2, N, bufA, w2hi, w2lo, bufB, N2, gGh);
    // 14. gemm3 second half
    gemm_half_k<64><<<gGh, blk, 0, stream>>>(bufA, w2hi, w2lo, dinv, bufB, N2, N);
    // 15. agg3 + bias + log_softmax
    agg_lsm_k<<<gW, blk, 0, stream>>>(bufB, offs, csr16, dinv, b2, out, N);
}

// Round 14
// 205.334 us; speedup vs baseline: 1.0266x; 1.0266x over previous
//
#include <hip/hip_runtime.h>
#include <math.h>

typedef __attribute__((ext_vector_type(8))) short bf16x8;
typedef __attribute__((ext_vector_type(4))) float f32x4;
typedef unsigned short u16;
typedef unsigned int u32;

static __device__ __forceinline__ u16 f2bf(float f) {
    unsigned u = __float_as_uint(f);
    unsigned r = (u + 0x7fff + ((u >> 16) & 1)) >> 16;  // RNE
    return (u16)r;
}
static __device__ __forceinline__ float bf2f(u16 h) {
    return __uint_as_float(((unsigned)h) << 16);
}
static __device__ __forceinline__ float pk_lo(u32 u) { return __uint_as_float(u << 16); }
static __device__ __forceinline__ float pk_hi(u32 u) { return __uint_as_float(u & 0xffff0000u); }

// ---------------- init: zero counts + pack weights ----------------
__global__ void init_k(int* __restrict__ counts, int n, int gN,
                       const float* __restrict__ W0, const float* __restrict__ W1,
                       const float* __restrict__ W2,
                       u16* __restrict__ w0hi, u16* __restrict__ w0lo,
                       u16* __restrict__ w1hi, u16* __restrict__ w1lo,
                       u16* __restrict__ w2hi, u16* __restrict__ w2lo) {
    int b = blockIdx.x;
    if (b < gN) {
        int i = b * 256 + threadIdx.x;
        if (i < n) counts[i] = 0;
        return;
    }
    int i = (b - gN) * 256 + threadIdx.x;
    const float* W; u16 *hi, *lo; int COLS, cin, idx;
    if (i < 16384)      { W = W0; hi = w0hi; lo = w0lo; COLS = 128; cin = 128; idx = i; }
    else if (i < 32768) { W = W1; hi = w1hi; lo = w1lo; COLS = 128; cin = 128; idx = i - 16384; }
    else if (i < 40960) { W = W2; hi = w2hi; lo = w2lo; COLS = 64;  cin = 40;  idx = i - 32768; }
    else return;
    int k = idx / COLS, col = idx % COLS;
    float v = (col < cin) ? W[k * cin + col] : 0.f;
    u16 h = f2bf(v);
    u16 l = f2bf(v - bf2f(h));
    int ct = col >> 4, ks = k >> 5, ln = (col & 15) + (((k >> 3) & 3) << 4), j = k & 7;
    int pos = (((ct * 4 + ks) * 64 + ln) << 3) + j;
    hi[pos] = h; lo[pos] = l;
}

// ---------------- layer-1 GEMM body: fp32 A, hi/lo 3-MFMA, UNSCALED bf16 C ----------------
static __device__ __forceinline__ void gemm1_body(int bid, const float* __restrict__ A,
                                                  const u16* __restrict__ Whi,
                                                  const u16* __restrict__ Wlo,
                                                  u16* __restrict__ C, int nrows) {
    constexpr int COLS = 128;
    int wave = threadIdx.x >> 6, lane = threadIdx.x & 63;
    int r0 = bid * 64 + wave * 16;
    int arow = min(r0 + (lane & 15), nrows - 1);
    int kbase = (lane >> 4) * 8;

    bf16x8 ahi[4], alo[4];
#pragma unroll
    for (int ks = 0; ks < 4; ++ks) {
        const float* ap = &A[(long)arow * 128 + ks * 32 + kbase];
        float4 f0 = *(const float4*)ap;
        float4 f1 = *(const float4*)(ap + 4);
        float fv[8] = {f0.x, f0.y, f0.z, f0.w, f1.x, f1.y, f1.z, f1.w};
#pragma unroll
        for (int j = 0; j < 8; ++j) {
            u16 h = f2bf(fv[j]);
            ahi[ks][j] = (short)h;
            alo[ks][j] = (short)f2bf(fv[j] - bf2f(h));
        }
    }
#pragma unroll
    for (int ct = 0; ct < COLS / 16; ct += 2) {
        f32x4 acc0 = {0.f, 0.f, 0.f, 0.f}, acc1 = {0.f, 0.f, 0.f, 0.f};
#pragma unroll
        for (int ks = 0; ks < 4; ++ks) {
            int fo0 = ((ct * 4 + ks) * 64 + lane) * 8;
            int fo1 = (((ct + 1) * 4 + ks) * 64 + lane) * 8;
            bf16x8 bhi0 = *(const bf16x8*)&Whi[fo0];
            bf16x8 blo0 = *(const bf16x8*)&Wlo[fo0];
            bf16x8 bhi1 = *(const bf16x8*)&Whi[fo1];
            bf16x8 blo1 = *(const bf16x8*)&Wlo[fo1];
            acc0 = __builtin_amdgcn_mfma_f32_16x16x32_bf16(ahi[ks], bhi0, acc0, 0, 0, 0);
            acc1 = __builtin_amdgcn_mfma_f32_16x16x32_bf16(ahi[ks], bhi1, acc1, 0, 0, 0);
            acc0 = __builtin_amdgcn_mfma_f32_16x16x32_bf16(alo[ks], bhi0, acc0, 0, 0, 0);
            acc1 = __builtin_amdgcn_mfma_f32_16x16x32_bf16(alo[ks], bhi1, acc1, 0, 0, 0);
            acc0 = __builtin_amdgcn_mfma_f32_16x16x32_bf16(ahi[ks], blo0, acc0, 0, 0, 0);
            acc1 = __builtin_amdgcn_mfma_f32_16x16x32_bf16(ahi[ks], blo1, acc1, 0, 0, 0);
        }
#pragma unroll
        for (int r = 0; r < 4; ++r) {
            int orow = r0 + (lane >> 4) * 4 + r;
            if (orow < nrows) {
                C[(long)orow * COLS + ct * 16 + (lane & 15)] = f2bf(acc0[r]);
                C[(long)orow * COLS + (ct + 1) * 16 + (lane & 15)] = f2bf(acc1[r]);
            }
        }
    }
}

// ---------------- D2: count+rank || layer-1 GEMM, interleaved 4:1 ----------------
__global__ __launch_bounds__(256) void cg1_k(const int* __restrict__ dst,
                                             int* __restrict__ counts,
                                             u16* __restrict__ rank, int e,
                                             const float* __restrict__ A,
                                             const u16* __restrict__ Whi,
                                             const u16* __restrict__ Wlo,
                                             u16* __restrict__ C, int nrows, int gemmBlocks) {
    int bid = blockIdx.x;
    int k = bid / 5, r = bid % 5;
    if (r == 4) {
        if (k < gemmBlocks) gemm1_body(k, A, Whi, Wlo, C, nrows);
        return;
    }
    int i = (k * 4 + r) * 256 + threadIdx.x;
    if (i < e) rank[i] = (u16)atomicAdd(&counts[dst[i]], 1);
}

// ---------------- scans ----------------
__global__ __launch_bounds__(1024) void scan1_k(const int* __restrict__ counts,
                                                int* __restrict__ offs,
                                                int* __restrict__ bsum,
                                                float* __restrict__ dinv, int n) {
    __shared__ int ws[16];
    int tid = threadIdx.x;
    int i = blockIdx.x * 1024 + tid;
    int lane = tid & 63, w = tid >> 6;
    int c = (i < n) ? counts[i] : 0;
    if (i < n) dinv[i] = rsqrtf((float)c + 1.0f);
    int s = c;
#pragma unroll
    for (int o = 1; o < 64; o <<= 1) { int t = __shfl_up(s, o); if (lane >= o) s += t; }
    if (lane == 63) ws[w] = s;
    __syncthreads();
    if (w == 0) {
        int x = (lane < 16) ? ws[lane] : 0;
#pragma unroll
        for (int o = 1; o < 16; o <<= 1) { int t = __shfl_up(x, o); if (lane >= o) x += t; }
        if (lane < 16) ws[lane] = x;
    }
    __syncthreads();
    int base = (w > 0) ? ws[w - 1] : 0;
    int incl = base + s;
    if (i < n) offs[i + 1] = incl;
    if (tid == 1023) bsum[blockIdx.x] = incl;
}
__global__ void scan23_k(int* __restrict__ offs, const int* __restrict__ bsum,
                         int nb, int n) {
    __shared__ int pre[64];
    int tid = threadIdx.x;
    if (tid < 64) {
        int v = (tid < nb) ? bsum[tid] : 0;
#pragma unroll
        for (int o = 1; o < 64; o <<= 1) { int t = __shfl_up(v, o); if (tid >= o) v += t; }
        pre[tid] = v;
    }
    __syncthreads();
    int i = blockIdx.x * 256 + tid;
    if (i == 0) offs[0] = 0;
    if (i < n) {
        int b = i >> 10;
        offs[i + 1] += (b > 0) ? pre[b - 1] : 0;
    }
}

// ---------------- D5: CSR fill || in-place dinv rescale, interleaved 2:1 ----------------
__global__ __launch_bounds__(256) void fr_k(const int* __restrict__ src,
                                            const int* __restrict__ dst,
                                            const u16* __restrict__ rank,
                                            const int* __restrict__ offs,
                                            u16* __restrict__ csr, int e,
                                            u16* __restrict__ Cs,
                                            const float* __restrict__ dinv, int n) {
    int bid = blockIdx.x;
    int k = bid / 3, r = bid % 3;
    if (r == 2) {
        int i = k * 256 + threadIdx.x;
        if (i < e) csr[offs[dst[i]] + (int)rank[i]] = (u16)src[i];
        return;
    }
    int t = (k * 2 + r) * 256 + threadIdx.x;   // one uint2 (4 bf16) per thread
    if (t >= n * 32) return;
    int row = t >> 5;
    float w = dinv[row];
    uint2 u = ((uint2*)Cs)[t];
    uint2 o2;
    o2.x = ((u32)f2bf(pk_hi(u.x) * w) << 16) | f2bf(pk_lo(u.x) * w);
    o2.y = ((u32)f2bf(pk_hi(u.y) * w) << 16) | f2bf(pk_lo(u.y) * w);
    ((uint2*)Cs)[t] = o2;
}

// ---------------- bf16-A GEMM body (2 MFMA), dinv-prescaled C, row range ----------------
template<int COLS>
static __device__ __forceinline__ void gemm_body(int bid, const u16* __restrict__ A,
                                                 const u16* __restrict__ Whi,
                                                 const u16* __restrict__ Wlo,
                                                 const float* __restrict__ dinv,
                                                 u16* __restrict__ C, int rowOff, int rowEnd) {
    int wave = threadIdx.x >> 6, lane = threadIdx.x & 63;
    int r0 = rowOff + bid * 64 + wave * 16;
    if (r0 >= rowEnd) return;
    int arow = min(r0 + (lane & 15), rowEnd - 1);
    int kbase = (lane >> 4) * 8;

    bf16x8 a[4];
#pragma unroll
    for (int ks = 0; ks < 4; ++ks)
        a[ks] = *(const bf16x8*)&A[(long)arow * 128 + ks * 32 + kbase];

    float dscale[4];
#pragma unroll
    for (int r = 0; r < 4; ++r) {
        int orow = r0 + (lane >> 4) * 4 + r;
        dscale[r] = (orow < rowEnd) ? dinv[orow] : 0.f;
    }
#pragma unroll
    for (int ct = 0; ct < COLS / 16; ct += 2) {
        f32x4 acc0 = {0.f, 0.f, 0.f, 0.f}, acc1 = {0.f, 0.f, 0.f, 0.f};
#pragma unroll
        for (int ks = 0; ks < 4; ++ks) {
            int fo0 = ((ct * 4 + ks) * 64 + lane) * 8;
            int fo1 = (((ct + 1) * 4 + ks) * 64 + lane) * 8;
            bf16x8 bhi0 = *(const bf16x8*)&Whi[fo0];
            bf16x8 blo0 = *(const bf16x8*)&Wlo[fo0];
            bf16x8 bhi1 = *(const bf16x8*)&Whi[fo1];
            bf16x8 blo1 = *(const bf16x8*)&Wlo[fo1];
            acc0 = __builtin_amdgcn_mfma_f32_16x16x32_bf16(a[ks], bhi0, acc0, 0, 0, 0);
            acc1 = __builtin_amdgcn_mfma_f32_16x16x32_bf16(a[ks], bhi1, acc1, 0, 0, 0);
            acc0 = __builtin_amdgcn_mfma_f32_16x16x32_bf16(a[ks], blo0, acc0, 0, 0, 0);
            acc1 = __builtin_amdgcn_mfma_f32_16x16x32_bf16(a[ks], blo1, acc1, 0, 0, 0);
        }
#pragma unroll
        for (int r = 0; r < 4; ++r) {
            int orow = r0 + (lane >> 4) * 4 + r;
            if (orow < rowEnd) {
                C[(long)orow * COLS + ct * 16 + (lane & 15)] = f2bf(acc0[r] * dscale[r]);
                C[(long)orow * COLS + (ct + 1) * 16 + (lane & 15)] = f2bf(acc1[r] * dscale[r]);
            }
        }
    }
}

// ---------------- agg + bias + LN + ReLU body (8-deep) ----------------
static __device__ __forceinline__ void agg_ln_body(int wid, int lane,
                                                   const u16* __restrict__ Cs,
                                                   const int* __restrict__ offs,
                                                   const u16* __restrict__ csr,
                                                   const float* __restrict__ dinv,
                                                   const float* __restrict__ bias,
                                                   const float* __restrict__ g,
                                                   const float* __restrict__ b,
                                                   u16* __restrict__ out) {
    const u32* C2 = (const u32*)Cs;
    u32 su = C2[(long)wid * 64 + lane];
    float ax = pk_lo(su), ay = pk_hi(su), bx2 = 0.f, by2 = 0.f;
    int beg = offs[wid], end = offs[wid + 1];
    int j = beg;
    while (j < end) {
        int take = min(64, end - j);
        int myidx = (lane < take) ? (int)csr[j + lane] : 0;
        int k = 0;
        for (; k + 8 <= take; k += 8) {
            int i0 = __shfl(myidx, k),     i1 = __shfl(myidx, k + 1);
            int i2 = __shfl(myidx, k + 2), i3 = __shfl(myidx, k + 3);
            int i4 = __shfl(myidx, k + 4), i5 = __shfl(myidx, k + 5);
            int i6 = __shfl(myidx, k + 6), i7 = __shfl(myidx, k + 7);
            u32 u0 = C2[(long)i0 * 64 + lane], u1 = C2[(long)i1 * 64 + lane];
            u32 u2 = C2[(long)i2 * 64 + lane], u3 = C2[(long)i3 * 64 + lane];
            u32 u4 = C2[(long)i4 * 64 + lane], u5 = C2[(long)i5 * 64 + lane];
            u32 u6 = C2[(long)i6 * 64 + lane], u7 = C2[(long)i7 * 64 + lane];
            ax += pk_lo(u0) + pk_lo(u1) + pk_lo(u2) + pk_lo(u3);
            ay += pk_hi(u0) + pk_hi(u1) + pk_hi(u2) + pk_hi(u3);
            bx2 += pk_lo(u4) + pk_lo(u5) + pk_lo(u6) + pk_lo(u7);
            by2 += pk_hi(u4) + pk_hi(u5) + pk_hi(u6) + pk_hi(u7);
        }
        for (; k < take; ++k) {
            int i0 = __shfl(myidx, k);
            u32 u0 = C2[(long)i0 * 64 + lane];
            ax += pk_lo(u0); ay += pk_hi(u0);
        }
        j += take;
    }
    float w = dinv[wid];
    float2 bia = ((const float2*)bias)[lane];
    float t0 = (ax + bx2) * w + bia.x;
    float t1 = (ay + by2) * w + bia.y;
    float s = t0 + t1;
#pragma unroll
    for (int off = 32; off; off >>= 1) s += __shfl_xor(s, off);
    float mu = s * (1.f / 128.f);
    float d0 = t0 - mu, d1 = t1 - mu;
    float v = d0 * d0 + d1 * d1;
#pragma unroll
    for (int off = 32; off; off >>= 1) v += __shfl_xor(v, off);
    float rstd = rsqrtf(v * (1.f / 128.f) + 1e-5f);
    float2 gv = ((const float2*)g)[lane];
    float2 bv = ((const float2*)b)[lane];
    float y0 = fmaxf(0.f, d0 * rstd * gv.x + bv.x);
    float y1 = fmaxf(0.f, d1 * rstd * gv.y + bv.y);
    ((u32*)out)[(long)wid * 64 + lane] = ((u32)f2bf(y1) << 16) | f2bf(y0);
}

// half-range agg dispatch
__global__ __launch_bounds__(256) void agg_half_k(const u16* __restrict__ Cs,
                                                  const int* __restrict__ offs,
                                                  const u16* __restrict__ csr,
                                                  const float* __restrict__ dinv,
                                                  const float* __restrict__ bias,
                                                  const float* __restrict__ g,
                                                  const float* __restrict__ b,
                                                  u16* __restrict__ out,
                                                  int nodeOff, int nodeEnd) {
    int wid = nodeOff + ((blockIdx.x * 256 + threadIdx.x) >> 6);
    int lane = threadIdx.x & 63;
    if (wid >= nodeEnd) return;
    agg_ln_body(wid, lane, Cs, offs, csr, dinv, bias, g, b, out);
}

// agg half || gemm half, interleaved 16:1
template<int COLS>
__global__ __launch_bounds__(256) void aggemm_k(const u16* __restrict__ CsAgg,
                                                const int* __restrict__ offs,
                                                const u16* __restrict__ csr,
                                                const float* __restrict__ dinv,
                                                const float* __restrict__ bias,
                                                const float* __restrict__ g,
                                                const float* __restrict__ b,
                                                u16* __restrict__ hOut,
                                                int nodeOff, int nodeEnd,
                                                const u16* __restrict__ A,
                                                const u16* __restrict__ Whi,
                                                const u16* __restrict__ Wlo,
                                                u16* __restrict__ C, int rowEnd, int gemmBlocks) {
    int bid = blockIdx.x;
    int k = bid / 17, r = bid % 17;
    if (r == 16) {
        if (k < gemmBlocks) gemm_body<COLS>(k, A, Whi, Wlo, dinv, C, 0, rowEnd);
        return;
    }
    int aggIdx = k * 16 + r;
    int wid = nodeOff + ((aggIdx * 256 + (int)threadIdx.x) >> 6);
    int lane = threadIdx.x & 63;
    if (wid >= nodeEnd) return;
    agg_ln_body(wid, lane, CsAgg, offs, csr, dinv, bias, g, b, hOut);
}

template<int COLS>
__global__ __launch_bounds__(256) void gemm_half_k(const u16* __restrict__ A,
                                                   const u16* __restrict__ Whi,
                                                   const u16* __restrict__ Wlo,
                                                   const float* __restrict__ dinv,
                                                   u16* __restrict__ C, int rowOff, int rowEnd) {
    gemm_body<COLS>(blockIdx.x, A, Whi, Wlo, dinv, C, rowOff, rowEnd);
}

// ---------------- agg + bias + log_softmax (8-deep, 64-col Cs) ----------------
__global__ __launch_bounds__(256) void agg_lsm_k(const u16* __restrict__ Cs,
                                                 const int* __restrict__ offs,
                                                 const u16* __restrict__ csr,
                                                 const float* __restrict__ dinv,
                                                 const float* __restrict__ b2,
                                                 float* __restrict__ out, int n) {
    int wid = (blockIdx.x * 256 + threadIdx.x) >> 6;
    int lane = threadIdx.x & 63;
    if (wid >= n) return;
    float aa = bf2f(Cs[(long)wid * 64 + lane]), ab = 0.f;
    int beg = offs[wid], end = offs[wid + 1];
    int j = beg;
    while (j < end) {
        int take = min(64, end - j);
        int myidx = (lane < take) ? (int)csr[j + lane] : 0;
        int k = 0;
        for (; k + 8 <= take; k += 8) {
            int i0 = __shfl(myidx, k),     i1 = __shfl(myidx, k + 1);
            int i2 = __shfl(myidx, k + 2), i3 = __shfl(myidx, k + 3);
            int i4 = __shfl(myidx, k + 4), i5 = __shfl(myidx, k + 5);
            int i6 = __shfl(myidx, k + 6), i7 = __shfl(myidx, k + 7);
            float v0 = bf2f(Cs[(long)i0 * 64 + lane]), v1 = bf2f(Cs[(long)i1 * 64 + lane]);
            float v2 = bf2f(Cs[(long)i2 * 64 + lane]), v3 = bf2f(Cs[(long)i3 * 64 + lane]);
            float v4 = bf2f(Cs[(long)i4 * 64 + lane]), v5 = bf2f(Cs[(long)i5 * 64 + lane]);
            float v6 = bf2f(Cs[(long)i6 * 64 + lane]), v7 = bf2f(Cs[(long)i7 * 64 + lane]);
            aa += v0 + v1 + v2 + v3;
            ab += v4 + v5 + v6 + v7;
        }
        for (; k < take; ++k) {
            int i0 = __shfl(myidx, k);
            aa += bf2f(Cs[(long)i0 * 64 + lane]);
        }
        j += take;
    }
    float v = (lane < 40) ? (aa + ab) * dinv[wid] + b2[lane] : -INFINITY;
    float m = v;
#pragma unroll
    for (int off = 32; off; off >>= 1) m = fmaxf(m, __shfl_xor(m, off));
    float e = (lane < 40) ? expf(v - m) : 0.f;
    float s = e;
#pragma unroll
    for (int off = 32; off; off >>= 1) s += __shfl_xor(s, off);
    float r = v - m - logf(s);
    if (lane < 40) out[(long)wid * 40 + lane] = r;
}

extern "C" void kernel_launch(void* const* d_in, const int* in_sizes, int n_in,
                              void* d_out, int out_size, void* d_ws, size_t ws_size,
                              hipStream_t stream) {
    const float* x    = (const float*)d_in[0];
    const float* W0   = (const float*)d_in[1];
    const float* b0   = (const float*)d_in[2];
    const float* W1   = (const float*)d_in[3];
    const float* b1   = (const float*)d_in[4];
    const float* W2   = (const float*)d_in[5];
    const float* b2   = (const float*)d_in[6];
    const float* ln1g = (const float*)d_in[7];
    const float* ln1b = (const float*)d_in[8];
    const float* ln2g = (const float*)d_in[9];
    const float* ln2b = (const float*)d_in[10];
    const int*   ei   = (const int*)d_in[11];

    const int N = in_sizes[0] / 128;   // 50000
    const int E = in_sizes[11] / 2;    // 800000
    const int* esrc = ei;
    const int* edst = ei + E;
    float* out = (float*)d_out;

    const int Npad = ((N + 255) / 256) * 256;
    const int N2 = N / 2;

    int* counts  = (int*)d_ws;                        // Npad
    int* offs    = counts + Npad;                     // Npad (N+1 used)
    int* bsum    = offs + Npad;                       // 64
    u16* rank16  = (u16*)(bsum + 64);                 // E
    u16* csr16   = rank16 + E;                        // E
    float* dinv  = (float*)(csr16 + E);               // Npad
    u16* bufA    = (u16*)(dinv + Npad);               // N*128 bf16  (Cs1, later h2)
    u16* bufB    = bufA + (size_t)N * 128;            // N*128 bf16  (h1, later Cs3[N][64])
    u16* bufC    = bufB + (size_t)N * 128;            // N*128 bf16  (Cs2)
    u16* w0hi    = bufC + (size_t)N * 128;
    u16* w0lo    = w0hi + 16384;
    u16* w1hi    = w0lo + 16384;
    u16* w1lo    = w1hi + 16384;
    u16* w2hi    = w1lo + 16384;
    u16* w2lo    = w2hi + 8192;

    dim3 blk(256);
    int gN = (N + 255) / 256;                 // 196
    int gE = (E + 255) / 256;                 // 3125
    int nb1024 = (N + 1023) / 1024;           // 49
    int gG = (N + 63) / 64;                   // 782 (full gemm)
    int gGh = (N2 + 63) / 64;                 // 391 (half gemm)
    int gAh = (N2 + 3) / 4;                   // 6250 (half agg)
    int gW = (N + 3) / 4;                     // 12500

    // 1. zero + weight prepack
    init_k<<<gN + 160, blk, 0, stream>>>(counts, N, gN, W0, W1, W2,
                                         w0hi, w0lo, w1hi, w1lo, w2hi, w2lo);
    // 2. count+rank || layer-1 GEMM (unscaled bf16), interleaved 4:1
    cg1_k<<<5 * gG, blk, 0, stream>>>(edst, counts, rank16, E,
                                      x, w0hi, w0lo, bufA, N, gG);
    // 3. block-local scan + dinv
    scan1_k<<<nb1024, 1024, 0, stream>>>(counts, offs, bsum, dinv, N);
    // 4. cross-block scan fixup
    scan23_k<<<gN, blk, 0, stream>>>(offs, bsum, nb1024, N);
    // 5. CSR fill || in-place Cs1 *= dinv[row], interleaved 2:1
    fr_k<<<3 * gE, blk, 0, stream>>>(esrc, edst, rank16, offs, csr16, E, bufA, dinv, N);
    // 6. agg1 first half: bufA -> h1 in bufB[0,N2)
    agg_half_k<<<gAh, blk, 0, stream>>>(bufA, offs, csr16, dinv, b0, ln1g, ln1b, bufB, 0, N2);
    // 7. agg1 second half || gemm2 first half (h1[0,N2) -> Cs2 bufC[0,N2))
    aggemm_k<128><<<17 * gGh, blk, 0, stream>>>(bufA, offs, csr16, dinv, b0, ln1g, ln1b, bufB,
                                                N2, N, bufB, w1hi, w1lo, bufC, N2, gGh);
    // 8. gemm2 second half: h1[N2,N) -> bufC[N2,N)
    gemm_half_k<128><<<gGh, blk, 0, stream>>>(bufB, w1hi, w1lo, dinv, bufC, N2, N);
    // 9. agg2 first half: bufC -> h2 in bufA[0,N2)
    agg_half_k<<<gAh, blk, 0, stream>>>(bufC, offs, csr16, dinv, b1, ln2g, ln2b, bufA, 0, N2);
    // 10. agg2 second half || gemm3 first half (h2[0,N2) -> Cs3 bufB64[0,N2))
    aggemm_k<64><<<17 * gGh, blk, 0, stream>>>(bufC, offs, csr16, dinv, b1, ln2g, ln2b, bufA,
                                               N2, N, bufA, w2hi, w2lo, bufB, N2, gGh);
    // 11. gemm3 second half: h2[N2,N) -> bufB64[N2,N)
    gemm_half_k<64><<<gGh, blk, 0, stream>>>(bufA, w2hi, w2lo, dinv, bufB, N2, N);
    // 12. agg3 + bias + log_softmax
    agg_lsm_k<<<gW, blk, 0, stream>>>(bufB, offs, csr16, dinv, b2, out, N);
}